// Round 12
// baseline (224.234 us; speedup 1.0000x reference)
//
#include <hip/hip_runtime.h>

constexpr int Bn = 4;
constexpr int Hn = 64;
constexpr int Wn = 64;
constexpr int LL = Hn * Wn;     // 4096
constexpr int DM = 128;
constexpr int DI = 256;
constexpr int Nn = 16;
constexpr int Rn = 8;
constexpr int Kn = 4;
constexpr int NC = 128;         // chunks per (b,k) scan  -- proven sweet spot (R0/R1)
constexpr int CHUNK = LL / NC;  // 32

using bf16x8 = __attribute__((ext_vector_type(8))) short;
using f32x4  = __attribute__((ext_vector_type(4))) float;
using f32x2  = __attribute__((ext_vector_type(2))) float;
using ushort4v = __attribute__((ext_vector_type(4))) unsigned short;

// ---------- helpers ----------
__device__ __forceinline__ float bf2f(unsigned short s) {
    return __uint_as_float(((unsigned int)s) << 16);
}
__device__ __forceinline__ unsigned short f2bf(float f) {
    unsigned int u = __float_as_uint(f);
    u += 0x7FFFu + ((u >> 16) & 1u);   // RNE
    return (unsigned short)(u >> 16);
}
__device__ __forceinline__ float softplus_f(float x) {
    if (x > 20.f) return x;
    return __logf(1.f + __expf(x));
}
// de = softplus(dtv), e1 = exp(-de) == 1/(1+exp(dtv))
__device__ __forceinline__ void softplus_e1(float dtv, float& de, float& e1) {
    float E = __expf(dtv);
    de = (dtv > 20.f) ? dtv : __logf(1.f + E);
    e1 = __builtin_amdgcn_rcpf(1.f + E);
}
// scan-order index t -> image position (row-major h*64+w)
__device__ __forceinline__ int posk(int k, int t) {
    int q = (k >= 2) ? (LL - 1 - t) : t;
    return (k & 1) ? (((q & 63) << 6) | (q >> 6)) : q;
}
// packed dot8: wr pre-packed as 4 x f32x2; rec 8B-aligned (k*40 floats = 160B)
__device__ __forceinline__ float dot8p(const f32x2 wr2[4], const float* rec) {
    const f32x2* r2 = (const f32x2*)rec;
    f32x2 s = wr2[0] * r2[0];
    s += wr2[1] * r2[1];
    s += wr2[2] * r2[2];
    s += wr2[3] * r2[3];
    return s.x + s.y;
}
// dot of pre-packed weight pairs with pre-loaded record pairs
__device__ __forceinline__ float dotr(const f32x2 wr2[4], const f32x2 rd[4]) {
    f32x2 s = wr2[0] * rd[0];
    s += wr2[1] * rd[1];
    s += wr2[2] * rd[2];
    s += wr2[3] * rd[3];
    return s.x + s.y;
}
__device__ __forceinline__ void load_wr2(const float* __restrict__ dtw, int kd, f32x2 wr2[4]) {
    f32x4 v0 = *(const f32x4*)(dtw + (size_t)kd * 8);
    f32x4 v1 = *(const f32x4*)(dtw + (size_t)kd * 8 + 4);
    wr2[0] = f32x2{v0.x, v0.y};
    wr2[1] = f32x2{v0.z, v0.w};
    wr2[2] = f32x2{v1.x, v1.y};
    wr2[3] = f32x2{v1.z, v1.w};
}
// pe[j] = {e1^(2j+1), e1^(2j+2)} for j=0..7, shallow independent tree (pk-fp32 friendly)
__device__ __forceinline__ void powpairs(float e1, f32x2 pe[8]) {
    float e2s = e1 * e1, e4s = e2s * e2s, e8s = e4s * e4s;
    f32x2 E2 = {e2s, e2s}, E4 = {e4s, e4s}, E8 = {e8s, e8s};
    pe[0] = f32x2{e1, e2s};
    pe[1] = pe[0] * E2;
    pe[2] = pe[0] * E4;
    pe[3] = pe[1] * E4;
    pe[4] = pe[0] * E8;
    pe[5] = pe[1] * E8;
    pe[6] = pe[2] * E8;
    pe[7] = pe[3] * E8;
}
// true iff -exp(A_logs[kd][n]) == -(n+1)  (A_logs = log(1..16) structure)
__device__ __forceinline__ bool check_chain(const float* __restrict__ A_logs, int kd) {
    float a0 = -__expf(A_logs[(size_t)kd * 16]);
    bool ok = fabsf(a0 + 1.f) < 1e-6f;
    #pragma unroll
    for (int n = 1; n < 16; ++n) {
        float an = -__expf(A_logs[(size_t)kd * 16 + n]);
        ok = ok && (fabsf(an - (float)(n + 1) * a0) <= 1e-4f * fabsf(an));
    }
    return ok;
}

// ---------- kernel 1: in_proj GEMM via MFMA bf16 — 64x64 tiles, grid 1024; emits bf16 ----------
__global__ __launch_bounds__(256) void k_inproj(const float* __restrict__ x,
                                                const float* __restrict__ wp,
                                                unsigned short* __restrict__ out) {
    __shared__ short sA[64][40];
    __shared__ short sW[64][40];
    int bid = blockIdx.x;
    int r0 = (bid >> 2) * 64;       // row tile (0..255)
    int c0 = (bid & 3) * 64;        // col group (0..3)
    int tid = threadIdx.x;
    int w = tid >> 6, lane = tid & 63;
    int ln15 = lane & 15, q8 = (lane >> 4) * 8;
    f32x4 acc[4];
    #pragma unroll
    for (int i = 0; i < 4; ++i) acc[i] = f32x4{0.f, 0.f, 0.f, 0.f};
    int r = tid >> 2, cc = (tid & 3) * 8;
    for (int kk = 0; kk < 4; ++kk) {
        {
            const float* src = x + (size_t)(r0 + r) * DM + kk * 32 + cc;
            float4 v0 = *(const float4*)src;
            float4 v1 = *(const float4*)(src + 4);
            bf16x8 s;
            s[0] = (short)f2bf(v0.x); s[1] = (short)f2bf(v0.y);
            s[2] = (short)f2bf(v0.z); s[3] = (short)f2bf(v0.w);
            s[4] = (short)f2bf(v1.x); s[5] = (short)f2bf(v1.y);
            s[6] = (short)f2bf(v1.z); s[7] = (short)f2bf(v1.w);
            *(bf16x8*)&sA[r][cc] = s;
        }
        {
            const float* src = wp + (size_t)(c0 + r) * DM + kk * 32 + cc;
            float4 v0 = *(const float4*)src;
            float4 v1 = *(const float4*)(src + 4);
            bf16x8 s;
            s[0] = (short)f2bf(v0.x); s[1] = (short)f2bf(v0.y);
            s[2] = (short)f2bf(v0.z); s[3] = (short)f2bf(v0.w);
            s[4] = (short)f2bf(v1.x); s[5] = (short)f2bf(v1.y);
            s[6] = (short)f2bf(v1.z); s[7] = (short)f2bf(v1.w);
            *(bf16x8*)&sW[r][cc] = s;
        }
        __syncthreads();
        bf16x8 a = *(bf16x8*)&sA[w * 16 + ln15][q8];
        #pragma unroll
        for (int ni = 0; ni < 4; ++ni) {
            bf16x8 bfr = *(bf16x8*)&sW[ni * 16 + ln15][q8];
            acc[ni] = __builtin_amdgcn_mfma_f32_16x16x32_bf16(a, bfr, acc[ni], 0, 0, 0);
        }
        __syncthreads();
    }
    int rbase = r0 + w * 16 + (lane >> 4) * 4;
    #pragma unroll
    for (int ni = 0; ni < 4; ++ni)
        #pragma unroll
        for (int rr = 0; rr < 4; ++rr)
            out[(size_t)(rbase + rr) * DI + c0 + ni * 16 + ln15] = f2bf(acc[ni][rr]);
}

// ---------- kernel 2: depthwise 3x3 conv + bias + SiLU — bf16 in, bf16 out ----------
__global__ __launch_bounds__(256) void k_conv(const unsigned short* __restrict__ xin,
                                              const float* __restrict__ cw,
                                              const float* __restrict__ cb,
                                              unsigned short* __restrict__ xoutB) {
    int bid = blockIdx.x;
    int band = bid & 3;
    int wblk = (bid >> 2) & 15;
    int dblk = (bid >> 6) & 3;
    int b    = bid >> 8;
    int tid = threadIdx.x;
    int d = dblk * 64 + (tid & 63);
    int w = wblk * 4 + (tid >> 6);
    const unsigned short* inb = xin + (size_t)b * LL * DI + d;
    unsigned short* outbB = xoutB + (size_t)b * LL * DI + d;
    float wg[9];
    #pragma unroll
    for (int i = 0; i < 9; ++i) wg[i] = cw[d * 9 + i];
    float bias = cb[d];
    #define LDV(hhh, www) ((((www) >= 0) && ((www) < Wn)) ? bf2f(inb[(size_t)((hhh) * Wn + (www)) * DI]) : 0.f)
    int hs = band * 16;
    float r0[3], r1[3], r2[3];
    if (hs == 0) { r0[0] = r0[1] = r0[2] = 0.f; }
    else { r0[0] = LDV(hs - 1, w - 1); r0[1] = LDV(hs - 1, w); r0[2] = LDV(hs - 1, w + 1); }
    r1[0] = LDV(hs, w - 1); r1[1] = LDV(hs, w); r1[2] = LDV(hs, w + 1);
    r2[0] = LDV(hs + 1, w - 1); r2[1] = LDV(hs + 1, w); r2[2] = LDV(hs + 1, w + 1);
    for (int h = hs; h < hs + 16; ++h) {
        float acc = bias + wg[0] * r0[0] + wg[1] * r0[1] + wg[2] * r0[2]
                         + wg[3] * r1[0] + wg[4] * r1[1] + wg[5] * r1[2]
                         + wg[6] * r2[0] + wg[7] * r2[1] + wg[8] * r2[2];
        float sig = 1.f / (1.f + __expf(-acc));
        outbB[(size_t)(h * Wn + w) * DI] = f2bf(acc * sig);
        r0[0] = r1[0]; r0[1] = r1[1]; r0[2] = r1[2];
        r1[0] = r2[0]; r1[1] = r2[1]; r1[2] = r2[2];
        if (h + 2 < Hn) { r2[0] = LDV(h + 2, w - 1); r2[1] = LDV(h + 2, w); r2[2] = LDV(h + 2, w + 1); }
        else { r2[0] = r2[1] = r2[2] = 0.f; }
    }
    #undef LDV
}

// ---------- kernel 3: projection GEMM via MFMA bf16 — 32-row tiles, grid 512, 2x2 waves ----------
__global__ __launch_bounds__(256) void k_proj(const unsigned short* __restrict__ xcB,
                                              const float* __restrict__ xpw,
                                              float* __restrict__ P) {
    __shared__ short sA[32][40];
    __shared__ short sW[160][40];
    int r0 = blockIdx.x * 32;
    int tid = threadIdx.x;
    int w = tid >> 6, lane = tid & 63;
    int ln15 = lane & 15, q8 = (lane >> 4) * 8;
    int wrh = w & 1;    // row half (16 rows)
    int wch = w >> 1;   // col half (5 ni tiles = 80 cols)
    f32x4 acc[5];
    #pragma unroll
    for (int i = 0; i < 5; ++i) acc[i] = f32x4{0.f, 0.f, 0.f, 0.f};
    for (int kk = 0; kk < 8; ++kk) {
        if (tid < 128) {
            int r = tid >> 2, cc = (tid & 3) * 8;
            *(bf16x8*)&sA[r][cc] =
                *(const bf16x8*)(xcB + (size_t)(r0 + r) * DI + kk * 32 + cc);
        }
        if (tid < 160) {
            const float* src = xpw + (size_t)tid * DI + kk * 32;
            #pragma unroll
            for (int j = 0; j < 8; ++j) {
                float4 v = *(const float4*)(src + j * 4);
                sW[tid][j * 4 + 0] = (short)f2bf(v.x);
                sW[tid][j * 4 + 1] = (short)f2bf(v.y);
                sW[tid][j * 4 + 2] = (short)f2bf(v.z);
                sW[tid][j * 4 + 3] = (short)f2bf(v.w);
            }
        }
        __syncthreads();
        bf16x8 a = *(bf16x8*)&sA[wrh * 16 + ln15][q8];
        #pragma unroll
        for (int ni = 0; ni < 5; ++ni) {
            bf16x8 bfr = *(bf16x8*)&sW[(wch * 5 + ni) * 16 + ln15][q8];
            acc[ni] = __builtin_amdgcn_mfma_f32_16x16x32_bf16(a, bfr, acc[ni], 0, 0, 0);
        }
        __syncthreads();
    }
    int rbase = r0 + wrh * 16 + (lane >> 4) * 4;
    #pragma unroll
    for (int ni = 0; ni < 5; ++ni)
        #pragma unroll
        for (int rr = 0; rr < 4; ++rr)
            P[(size_t)(rbase + rr) * 160 + (wch * 5 + ni) * 16 + ln15] = acc[ni][rr];
}

// ---------- scan step cores ----------
// Phase A single-step (R9 form): state chain only. Reads rec[0..24): dts(8) + B(16).
template <bool CHAIN>
__device__ __forceinline__ void sA_step(const float* __restrict__ rec, float u,
                                        const f32x2 wr2[4], float bias,
                                        const float* __restrict__ A_logs, int kd,
                                        f32x2 h2[8], float& sde) {
    float dtv = bias + dot8p(wr2, rec);
    float de, e1;
    softplus_e1(dtv, de, e1);
    float du = de * u;
    sde += de;
    f32x2 Ba[8];
    #pragma unroll
    for (int i = 0; i < 4; ++i) {
        f32x4 v = *(const f32x4*)(rec + 8 + i * 4);
        Ba[2 * i]     = f32x2{v.x, v.y};
        Ba[2 * i + 1] = f32x2{v.z, v.w};
    }
    f32x2 du2 = {du, du};
    if constexpr (CHAIN) {
        f32x2 pe[8];
        powpairs(e1, pe);
        #pragma unroll
        for (int j = 0; j < 8; ++j) {
            f32x2 t = du2 * Ba[j];
            h2[j] = pe[j] * h2[j] + t;
        }
    } else {
        #pragma unroll
        for (int j = 0; j < 8; ++j) {
            float A0 = -__expf(A_logs[(size_t)kd * 16 + 2 * j]);
            float A1 = -__expf(A_logs[(size_t)kd * 16 + 2 * j + 1]);
            f32x2 dec = {__expf(de * A0), __expf(de * A1)};
            f32x2 t = du2 * Ba[j];
            h2[j] = dec * h2[j] + t;
        }
    }
}
// Phase C pair-step (R10 form): full chains + two y outputs. Record (40 floats) loaded once.
template <bool CHAIN>
__device__ __forceinline__ void sC_step2(const float* __restrict__ rec, float uA, float uB,
                                         const f32x2 wr2A[4], const f32x2 wr2B[4],
                                         float biasA, float biasB, float DvA, float DvB,
                                         const float* __restrict__ A_logs, int kdA, int kdB,
                                         f32x2 hA[8], f32x2 hB[8],
                                         float& yA, float& yB) {
    f32x2 rd[4];
    {
        const f32x2* r2 = (const f32x2*)rec;
        rd[0] = r2[0]; rd[1] = r2[1]; rd[2] = r2[2]; rd[3] = r2[3];
    }
    f32x2 Ba[8], Ca[8];
    #pragma unroll
    for (int i = 0; i < 4; ++i) {
        f32x4 v = *(const f32x4*)(rec + 8 + i * 4);
        Ba[2 * i]     = f32x2{v.x, v.y};
        Ba[2 * i + 1] = f32x2{v.z, v.w};
        f32x4 w = *(const f32x4*)(rec + 24 + i * 4);
        Ca[2 * i]     = f32x2{w.x, w.y};
        Ca[2 * i + 1] = f32x2{w.z, w.w};
    }
    float dtvA = biasA + dotr(wr2A, rd);
    float dtvB = biasB + dotr(wr2B, rd);
    float deA, e1A, deB, e1B;
    softplus_e1(dtvA, deA, e1A);
    softplus_e1(dtvB, deB, e1B);
    float duA = deA * uA, duB = deB * uB;
    f32x2 duA2 = {duA, duA}, duB2 = {duB, duB};
    f32x2 yvA[2], yvB[2];
    yvA[0] = f32x2{DvA * uA, 0.f}; yvA[1] = f32x2{0.f, 0.f};
    yvB[0] = f32x2{DvB * uB, 0.f}; yvB[1] = f32x2{0.f, 0.f};
    if constexpr (CHAIN) {
        f32x2 peA[8], peB[8];
        powpairs(e1A, peA);
        powpairs(e1B, peB);
        #pragma unroll
        for (int j = 0; j < 8; ++j) {
            hA[j] = peA[j] * hA[j] + duA2 * Ba[j];
            hB[j] = peB[j] * hB[j] + duB2 * Ba[j];
            yvA[j & 1] += hA[j] * Ca[j];
            yvB[j & 1] += hB[j] * Ca[j];
        }
    } else {
        #pragma unroll
        for (int j = 0; j < 8; ++j) {
            float A0a = -__expf(A_logs[(size_t)kdA * 16 + 2 * j]);
            float A1a = -__expf(A_logs[(size_t)kdA * 16 + 2 * j + 1]);
            float A0b = -__expf(A_logs[(size_t)kdB * 16 + 2 * j]);
            float A1b = -__expf(A_logs[(size_t)kdB * 16 + 2 * j + 1]);
            f32x2 decA = {__expf(deA * A0a), __expf(deA * A1a)};
            f32x2 decB = {__expf(deB * A0b), __expf(deB * A1b)};
            hA[j] = decA * hA[j] + duA2 * Ba[j];
            hB[j] = decB * hB[j] + duB2 * Ba[j];
            yvA[j & 1] += hA[j] * Ca[j];
            yvB[j & 1] += hB[j] * Ca[j];
        }
    }
    f32x2 sA2 = yvA[0] + yvA[1];
    f32x2 sB2 = yvB[0] + yvB[1];
    yA = sA2.x + sA2.y;
    yB = sB2.x + sB2.y;
}

// ---------- kernel 4: phase A — per-chunk state summaries only (R9 structure, unpaired) ----------
// grid 2048 = 4b * 4k * 128c ; block 256 ; no LDS, no y output.
__global__ __launch_bounds__(256, 8) void k_scanA(const unsigned short* __restrict__ xcB,
                                                  const float* __restrict__ P,
                                                  const float* __restrict__ dtw,
                                                  const float* __restrict__ dtb,
                                                  const float* __restrict__ A_logs,
                                                  float* __restrict__ carrG,
                                                  unsigned short* __restrict__ carrH) {
    int bid = blockIdx.x;
    int c = bid & (NC - 1);
    int k = (bid >> 7) & 3;
    int b = bid >> 9;
    int tid = threadIdx.x;
    int kd = k * DI + tid;
    f32x2 wr2[4];
    load_wr2(dtw, kd, wr2);
    float bias = dtb[kd];
    bool ch = check_chain(A_logs, kd);
    f32x2 h2[8];
    #pragma unroll
    for (int j = 0; j < 8; ++j) h2[j] = f32x2{0.f, 0.f};
    float sde = 0.f;
    int t0 = c * CHUNK;
    int p0 = posk(k, t0), dp = posk(k, t0 + 1) - p0;
    const float* rec = P + ((size_t)b * LL + p0) * 160 + k * 40;
    const unsigned short* up = xcB + ((size_t)b * LL + p0) * DI + tid;
    long rs = (long)dp * 160, us = (long)dp * DI;
    if (ch) {
        for (int tt = 0; tt < CHUNK; ++tt) {
            sA_step<true>(rec, bf2f(*up), wr2, bias, A_logs, kd, h2, sde);
            rec += rs; up += us;
        }
    } else {
        for (int tt = 0; tt < CHUNK; ++tt) {
            sA_step<false>(rec, bf2f(*up), wr2, bias, A_logs, kd, h2, sde);
            rec += rs; up += us;
        }
    }
    // carries (chunk index in the direction's own scan order)
    carrG[((size_t)(b * Kn + k) * NC + c) * DI + tid] = sde;
    size_t hb = ((size_t)(b * Kn + k) * NC + c) * 16 * DI + tid;
    #pragma unroll
    for (int j = 0; j < 8; ++j) {
        carrH[hb + (size_t)(2 * j) * DI]     = f2bf(h2[j].x);
        carrH[hb + (size_t)(2 * j + 1) * DI] = f2bf(h2[j].y);
    }
}

// ---------- kernel 5: scan phase 2 — combine carries across chunks ----------
__global__ __launch_bounds__(256) void k_scan2(const float* __restrict__ carrG,
                                               const float* __restrict__ A_logs,
                                               unsigned short* __restrict__ carrH) {
    int gid = blockIdx.x * 256 + threadIdx.x;
    int d = gid & 255;
    int n = (gid >> 8) & 15;
    int bk = gid >> 12;
    int k = bk & 3;
    float Ac = -__expf(A_logs[(size_t)(k * DI + d) * 16 + n]);
    size_t gbase = (size_t)bk * NC * DI + d;
    size_t hbase = ((size_t)bk * NC * 16 + n) * DI + d;
    const size_t hs = (size_t)16 * DI;
    float hr = 0.f;
    #pragma unroll
    for (int g = 0; g < NC / 32; ++g) {
        float sv[32];
        unsigned short hvv[32];
        #pragma unroll
        for (int j = 0; j < 32; ++j) sv[j] = carrG[gbase + (size_t)(g * 32 + j) * DI];
        #pragma unroll
        for (int j = 0; j < 32; ++j) hvv[j] = carrH[hbase + (size_t)(g * 32 + j) * hs];
        #pragma unroll
        for (int j = 0; j < 32; ++j) {
            float a = __expf(Ac * sv[j]);
            float he = bf2f(hvv[j]);
            carrH[hbase + (size_t)(g * 32 + j) * hs] = f2bf(hr);
            hr = a * hr + he;
        }
    }
}

// ---------- kernel 6: phase C — full chain with combined h0, 2 d/thread; all-bf16 y out ----------
// grid 2048 = 4b * 4k * 128c ; block 128 threads. Outputs per-direction (all bf16):
// k=0 -> y0 (row-major), k=1 -> y1 (wh order), k=2 -> y2 (row-major), k=3 -> y3 (wh order)
__global__ __launch_bounds__(128, 4) void k_scanC(const unsigned short* __restrict__ xcB,
                                                  const float* __restrict__ P,
                                                  const float* __restrict__ dtw,
                                                  const float* __restrict__ dtb,
                                                  const float* __restrict__ A_logs,
                                                  const float* __restrict__ Ds,
                                                  const unsigned short* __restrict__ carrH,
                                                  unsigned short* __restrict__ y0,
                                                  unsigned short* __restrict__ y1,
                                                  unsigned short* __restrict__ y2,
                                                  unsigned short* __restrict__ y3) {
    int bid = blockIdx.x;
    int c = bid & (NC - 1);
    int k = (bid >> 7) & 3;
    int b = bid >> 9;
    int tid = threadIdx.x;          // 0..127
    int kdA = k * DI + tid, kdB = kdA + 128;
    f32x2 wr2A[4], wr2B[4];
    load_wr2(dtw, kdA, wr2A);
    load_wr2(dtw, kdB, wr2B);
    float biasA = dtb[kdA], biasB = dtb[kdB];
    float DvA = Ds[kdA], DvB = Ds[kdB];
    bool ch = check_chain(A_logs, kdA) && check_chain(A_logs, kdB);
    // h0 = prefix-combined incoming state for this chunk
    f32x2 hA[8], hB[8];
    size_t hb = ((size_t)(b * Kn + k) * NC + c) * 16 * DI + tid;
    #pragma unroll
    for (int j = 0; j < 8; ++j) {
        hA[j] = f32x2{bf2f(carrH[hb + (size_t)(2 * j) * DI]),
                      bf2f(carrH[hb + (size_t)(2 * j + 1) * DI])};
        hB[j] = f32x2{bf2f(carrH[hb + 128 + (size_t)(2 * j) * DI]),
                      bf2f(carrH[hb + 128 + (size_t)(2 * j + 1) * DI])};
    }
    int t0 = c * CHUNK;
    int p0 = posk(k, t0), dp = posk(k, t0 + 1) - p0;
    const float* rec = P + ((size_t)b * LL + p0) * 160 + k * 40;
    const unsigned short* up = xcB + ((size_t)b * LL + p0) * DI + tid;
    long rs = (long)dp * 160, us = (long)dp * DI;
    // output stream (block-uniform selection); chain B is +128 elements; all bf16
    bool rev = (k >= 2);
    size_t i0 = rev ? (size_t)(LL - 1 - t0) : (size_t)t0;
    long ystepB = rev ? -(long)DI * 2 : (long)DI * 2;
    unsigned short* yb;
    if (k == 0)      yb = y0;
    else if (k == 1) yb = y1;
    else if (k == 2) yb = y2;
    else             yb = y3;
    char* yp = (char*)(yb + ((size_t)b * LL + i0) * DI + tid);
    if (ch) {
        for (int tt = 0; tt < CHUNK; ++tt) {
            float yA, yB;
            sC_step2<true>(rec, bf2f(up[0]), bf2f(up[128]), wr2A, wr2B, biasA, biasB,
                           DvA, DvB, A_logs, kdA, kdB, hA, hB, yA, yB);
            rec += rs; up += us;
            *(unsigned short*)yp = f2bf(yA);
            *(unsigned short*)(yp + 256) = f2bf(yB);
            yp += ystepB;
        }
    } else {
        for (int tt = 0; tt < CHUNK; ++tt) {
            float yA, yB;
            sC_step2<false>(rec, bf2f(up[0]), bf2f(up[128]), wr2A, wr2B, biasA, biasB,
                            DvA, DvB, A_logs, kdA, kdB, hA, hB, yA, yB);
            rec += rs; up += us;
            *(unsigned short*)yp = f2bf(yA);
            *(unsigned short*)(yp + 256) = f2bf(yB);
            yp += ystepB;
        }
    }
}

// ---------- kernel 7: LayerNorm — combine 4 bf16 direction buffers, write f32 d_out ----------
// grid 4096 = 16384 rows / 4 rows per block ; block 256 = 4 waves
__global__ __launch_bounds__(256) void k_ln(float* __restrict__ y,
                                            const unsigned short* __restrict__ y0,
                                            const unsigned short* __restrict__ y1,
                                            const unsigned short* __restrict__ y2,
                                            const unsigned short* __restrict__ y3,
                                            const float* __restrict__ gamma,
                                            const float* __restrict__ beta) {
    int tid = threadIdx.x;
    int w = tid >> 6, lane = tid & 63;
    int r = blockIdx.x * 4 + w;
    int b = r >> 12;
    int pos = r & 4095;
    int q = ((pos & 63) << 6) | (pos >> 6);   // y1/y3 are stored in wh-scan order
    ushort4v v0v = *(const ushort4v*)(y0 + (size_t)r * DI + lane * 4);
    ushort4v v2 = *(const ushort4v*)(y2 + (size_t)r * DI + lane * 4);
    ushort4v v1 = *(const ushort4v*)(y1 + ((size_t)b * LL + q) * DI + lane * 4);
    ushort4v v3 = *(const ushort4v*)(y3 + ((size_t)b * LL + q) * DI + lane * 4);
    float v0 = bf2f(v0v.x) + bf2f(v2.x) + bf2f(v1.x) + bf2f(v3.x);
    float vv1 = bf2f(v0v.y) + bf2f(v2.y) + bf2f(v1.y) + bf2f(v3.y);
    float vv2 = bf2f(v0v.z) + bf2f(v2.z) + bf2f(v1.z) + bf2f(v3.z);
    float vv3 = bf2f(v0v.w) + bf2f(v2.w) + bf2f(v1.w) + bf2f(v3.w);
    float a = (v0 + vv1) + (vv2 + vv3);
    float bsq = (v0 * v0 + vv1 * vv1) + (vv2 * vv2 + vv3 * vv3);
    #pragma unroll
    for (int off = 32; off; off >>= 1) {
        a += __shfl_xor(a, off);
        bsq += __shfl_xor(bsq, off);
    }
    float mu = a * (1.f / 256.f);
    float var = bsq * (1.f / 256.f) - mu * mu;
    float rs = rsqrtf(var + 1e-5f);
    float4 gm = *(const float4*)(gamma + lane * 4);
    float4 bt = *(const float4*)(beta + lane * 4);
    float4 o;
    o.x = (v0 - mu) * rs * gm.x + bt.x;
    o.y = (vv1 - mu) * rs * gm.y + bt.y;
    o.z = (vv2 - mu) * rs * gm.z + bt.z;
    o.w = (vv3 - mu) * rs * gm.w + bt.w;
    *(float4*)(y + (size_t)r * DI + lane * 4) = o;
}

// ---------- launch ----------
extern "C" void kernel_launch(void* const* d_in, const int* in_sizes, int n_in,
                              void* d_out, int out_size, void* d_ws, size_t ws_size,
                              hipStream_t stream) {
    const float* x    = (const float*)d_in[0];
    const float* ipw  = (const float*)d_in[1];
    const float* cw   = (const float*)d_in[2];
    const float* cb   = (const float*)d_in[3];
    const float* xpw  = (const float*)d_in[4];
    const float* dtw  = (const float*)d_in[5];
    const float* dtb  = (const float*)d_in[6];
    const float* alog = (const float*)d_in[7];
    const float* Ds   = (const float*)d_in[8];
    const float* gam  = (const float*)d_in[9];
    const float* bet  = (const float*)d_in[10];

    // ws layout (bytes):
    //   [0, 16777216)           carrH (bf16) -- aliases xls_preB (in_proj out bf16, dead after conv)
    //   [16777216, 18874368)    carrG (fp32)
    //   [18874368, 27262976)    xcB   (bf16 B*L*DI)
    //   [27262976, 37748736)    P     (fp32 B*L*160, image order: [k*40: dts|B|C])
    //   [37748736, 46137344)    y0    (bf16 B*L*DI, dir0 row-major)
    //   [46137344, 54525952)    y1    (bf16 B*L*DI, dir1 wh-scan order)
    //   [54525952, 62914560)    y2    (bf16 B*L*DI, dir2 row-major)
    //   [62914560, 71303168)    y3    (bf16 B*L*DI, dir3 wh-scan order)
    const size_t WS_NEED = 71303168;   // R1 proved ws_size >= 73400320
    if (ws_size < WS_NEED) return;

    char* ws = (char*)d_ws;
    unsigned short* carrH = (unsigned short*)(ws + 0);
    unsigned short* xls_preB = (unsigned short*)(ws + 0);   // alias: dead after conv
    float* carrG   = (float*)(ws + 16777216);
    unsigned short* xcB = (unsigned short*)(ws + 18874368);
    float* P       = (float*)(ws + 27262976);
    unsigned short* y0 = (unsigned short*)(ws + 37748736);
    unsigned short* y1 = (unsigned short*)(ws + 46137344);
    unsigned short* y2 = (unsigned short*)(ws + 54525952);
    unsigned short* y3 = (unsigned short*)(ws + 62914560);
    float* y       = (float*)d_out;

    k_inproj<<<1024,  256, 0, stream>>>(x, ipw, xls_preB);
    k_conv  <<<1024,  256, 0, stream>>>(xls_preB, cw, cb, xcB);
    k_proj  <<<512,   256, 0, stream>>>(xcB, xpw, P);
    k_scanA <<<2048,  256, 0, stream>>>(xcB, P, dtw, dtb, alog, carrG, carrH);
    k_scan2 <<<256,   256, 0, stream>>>(carrG, alog, carrH);
    k_scanC <<<2048,  128, 0, stream>>>(xcB, P, dtw, dtb, alog, Ds, carrH, y0, y1, y2, y3);
    k_ln    <<<4096,  256, 0, stream>>>(y, y0, y1, y2, y3, gam, bet);
}

// Round 14
// 214.915 us; speedup vs baseline: 1.0434x; 1.0434x over previous
//
#include <hip/hip_runtime.h>

constexpr int Bn = 4;
constexpr int Hn = 64;
constexpr int Wn = 64;
constexpr int LL = Hn * Wn;     // 4096
constexpr int DM = 128;
constexpr int DI = 256;
constexpr int Nn = 16;
constexpr int Rn = 8;
constexpr int Kn = 4;
constexpr int NC = 128;         // chunks per (b,k) scan  -- proven sweet spot (R0/R1)
constexpr int CHUNK = LL / NC;  // 32

using bf16x8 = __attribute__((ext_vector_type(8))) short;
using f32x4  = __attribute__((ext_vector_type(4))) float;
using f32x2  = __attribute__((ext_vector_type(2))) float;
using ushort4v = __attribute__((ext_vector_type(4))) unsigned short;

// ---------- helpers ----------
__device__ __forceinline__ float bf2f(unsigned short s) {
    return __uint_as_float(((unsigned int)s) << 16);
}
__device__ __forceinline__ unsigned short f2bf(float f) {
    unsigned int u = __float_as_uint(f);
    u += 0x7FFFu + ((u >> 16) & 1u);   // RNE
    return (unsigned short)(u >> 16);
}
__device__ __forceinline__ float softplus_f(float x) {
    if (x > 20.f) return x;
    return __logf(1.f + __expf(x));
}
// de = softplus(dtv), e1 = exp(-de) == 1/(1+exp(dtv))
__device__ __forceinline__ void softplus_e1(float dtv, float& de, float& e1) {
    float E = __expf(dtv);
    de = (dtv > 20.f) ? dtv : __logf(1.f + E);
    e1 = __builtin_amdgcn_rcpf(1.f + E);
}
// scan-order index t -> image position (row-major h*64+w)
__device__ __forceinline__ int posk(int k, int t) {
    int q = (k >= 2) ? (LL - 1 - t) : t;
    return (k & 1) ? (((q & 63) << 6) | (q >> 6)) : q;
}
// packed dot8: wr pre-packed as 4 x f32x2; rec 8B-aligned (k*40 floats = 160B)
__device__ __forceinline__ float dot8p(const f32x2 wr2[4], const float* rec) {
    const f32x2* r2 = (const f32x2*)rec;
    f32x2 s = wr2[0] * r2[0];
    s += wr2[1] * r2[1];
    s += wr2[2] * r2[2];
    s += wr2[3] * r2[3];
    return s.x + s.y;
}
// dot of pre-packed weight pairs with pre-loaded record pairs
__device__ __forceinline__ float dotr(const f32x2 wr2[4], const f32x2 rd[4]) {
    f32x2 s = wr2[0] * rd[0];
    s += wr2[1] * rd[1];
    s += wr2[2] * rd[2];
    s += wr2[3] * rd[3];
    return s.x + s.y;
}
__device__ __forceinline__ void load_wr2(const float* __restrict__ dtw, int kd, f32x2 wr2[4]) {
    f32x4 v0 = *(const f32x4*)(dtw + (size_t)kd * 8);
    f32x4 v1 = *(const f32x4*)(dtw + (size_t)kd * 8 + 4);
    wr2[0] = f32x2{v0.x, v0.y};
    wr2[1] = f32x2{v0.z, v0.w};
    wr2[2] = f32x2{v1.x, v1.y};
    wr2[3] = f32x2{v1.z, v1.w};
}
// pe[j] = {e1^(2j+1), e1^(2j+2)} for j=0..7, shallow independent tree (pk-fp32 friendly)
__device__ __forceinline__ void powpairs(float e1, f32x2 pe[8]) {
    float e2s = e1 * e1, e4s = e2s * e2s, e8s = e4s * e4s;
    f32x2 E2 = {e2s, e2s}, E4 = {e4s, e4s}, E8 = {e8s, e8s};
    pe[0] = f32x2{e1, e2s};
    pe[1] = pe[0] * E2;
    pe[2] = pe[0] * E4;
    pe[3] = pe[1] * E4;
    pe[4] = pe[0] * E8;
    pe[5] = pe[1] * E8;
    pe[6] = pe[2] * E8;
    pe[7] = pe[3] * E8;
}
// true iff -exp(A_logs[kd][n]) == -(n+1)  (A_logs = log(1..16) structure)
__device__ __forceinline__ bool check_chain(const float* __restrict__ A_logs, int kd) {
    float a0 = -__expf(A_logs[(size_t)kd * 16]);
    bool ok = fabsf(a0 + 1.f) < 1e-6f;
    #pragma unroll
    for (int n = 1; n < 16; ++n) {
        float an = -__expf(A_logs[(size_t)kd * 16 + n]);
        ok = ok && (fabsf(an - (float)(n + 1) * a0) <= 1e-4f * fabsf(an));
    }
    return ok;
}
// load a full 40-float record as packed pairs (dts 8 | B 16 | C 16)
__device__ __forceinline__ void loadC_rec(const float* __restrict__ rec,
                                          f32x2 rd[4], f32x2 Ba[8], f32x2 Ca[8]) {
    const f32x2* r2 = (const f32x2*)rec;
    #pragma unroll
    for (int j = 0; j < 4; ++j) rd[j] = r2[j];
    #pragma unroll
    for (int i = 0; i < 4; ++i) {
        f32x4 v = *(const f32x4*)(rec + 8 + i * 4);
        Ba[2 * i]     = f32x2{v.x, v.y};
        Ba[2 * i + 1] = f32x2{v.z, v.w};
        f32x4 w = *(const f32x4*)(rec + 24 + i * 4);
        Ca[2 * i]     = f32x2{w.x, w.y};
        Ca[2 * i + 1] = f32x2{w.z, w.w};
    }
}

// ---------- kernel 1: in_proj GEMM via MFMA bf16 — 64x64 tiles, grid 1024 (4 blocks/CU) ----------
__global__ __launch_bounds__(256) void k_inproj(const float* __restrict__ x,
                                                const float* __restrict__ wp,
                                                float* __restrict__ out) {
    __shared__ short sA[64][40];
    __shared__ short sW[64][40];
    int bid = blockIdx.x;
    int r0 = (bid >> 2) * 64;       // row tile (0..255)
    int c0 = (bid & 3) * 64;        // col group (0..3)
    int tid = threadIdx.x;
    int w = tid >> 6, lane = tid & 63;
    int ln15 = lane & 15, q8 = (lane >> 4) * 8;
    f32x4 acc[4];
    #pragma unroll
    for (int i = 0; i < 4; ++i) acc[i] = f32x4{0.f, 0.f, 0.f, 0.f};
    int r = tid >> 2, cc = (tid & 3) * 8;
    for (int kk = 0; kk < 4; ++kk) {
        {
            const float* src = x + (size_t)(r0 + r) * DM + kk * 32 + cc;
            float4 v0 = *(const float4*)src;
            float4 v1 = *(const float4*)(src + 4);
            bf16x8 s;
            s[0] = (short)f2bf(v0.x); s[1] = (short)f2bf(v0.y);
            s[2] = (short)f2bf(v0.z); s[3] = (short)f2bf(v0.w);
            s[4] = (short)f2bf(v1.x); s[5] = (short)f2bf(v1.y);
            s[6] = (short)f2bf(v1.z); s[7] = (short)f2bf(v1.w);
            *(bf16x8*)&sA[r][cc] = s;
        }
        {
            const float* src = wp + (size_t)(c0 + r) * DM + kk * 32 + cc;
            float4 v0 = *(const float4*)src;
            float4 v1 = *(const float4*)(src + 4);
            bf16x8 s;
            s[0] = (short)f2bf(v0.x); s[1] = (short)f2bf(v0.y);
            s[2] = (short)f2bf(v0.z); s[3] = (short)f2bf(v0.w);
            s[4] = (short)f2bf(v1.x); s[5] = (short)f2bf(v1.y);
            s[6] = (short)f2bf(v1.z); s[7] = (short)f2bf(v1.w);
            *(bf16x8*)&sW[r][cc] = s;
        }
        __syncthreads();
        bf16x8 a = *(bf16x8*)&sA[w * 16 + ln15][q8];
        #pragma unroll
        for (int ni = 0; ni < 4; ++ni) {
            bf16x8 bfr = *(bf16x8*)&sW[ni * 16 + ln15][q8];
            acc[ni] = __builtin_amdgcn_mfma_f32_16x16x32_bf16(a, bfr, acc[ni], 0, 0, 0);
        }
        __syncthreads();
    }
    int rbase = r0 + w * 16 + (lane >> 4) * 4;
    #pragma unroll
    for (int ni = 0; ni < 4; ++ni)
        #pragma unroll
        for (int rr = 0; rr < 4; ++rr)
            out[(size_t)(rbase + rr) * DI + c0 + ni * 16 + ln15] = acc[ni][rr];
}

// ---------- kernel 2: depthwise 3x3 conv + bias + SiLU — 16-row bands, grid 1024 ----------
__global__ __launch_bounds__(256) void k_conv(const float* __restrict__ xin,
                                              const float* __restrict__ cw,
                                              const float* __restrict__ cb,
                                              unsigned short* __restrict__ xoutB) {
    int bid = blockIdx.x;
    int band = bid & 3;
    int wblk = (bid >> 2) & 15;
    int dblk = (bid >> 6) & 3;
    int b    = bid >> 8;
    int tid = threadIdx.x;
    int d = dblk * 64 + (tid & 63);
    int w = wblk * 4 + (tid >> 6);
    const float* inb = xin + (size_t)b * LL * DI + d;
    unsigned short* outbB = xoutB + (size_t)b * LL * DI + d;
    float wg[9];
    #pragma unroll
    for (int i = 0; i < 9; ++i) wg[i] = cw[d * 9 + i];
    float bias = cb[d];
    #define LDV(hhh, www) ((((www) >= 0) && ((www) < Wn)) ? inb[(size_t)((hhh) * Wn + (www)) * DI] : 0.f)
    int hs = band * 16;
    float r0[3], r1[3], r2[3];
    if (hs == 0) { r0[0] = r0[1] = r0[2] = 0.f; }
    else { r0[0] = LDV(hs - 1, w - 1); r0[1] = LDV(hs - 1, w); r0[2] = LDV(hs - 1, w + 1); }
    r1[0] = LDV(hs, w - 1); r1[1] = LDV(hs, w); r1[2] = LDV(hs, w + 1);
    r2[0] = LDV(hs + 1, w - 1); r2[1] = LDV(hs + 1, w); r2[2] = LDV(hs + 1, w + 1);
    for (int h = hs; h < hs + 16; ++h) {
        float acc = bias + wg[0] * r0[0] + wg[1] * r0[1] + wg[2] * r0[2]
                         + wg[3] * r1[0] + wg[4] * r1[1] + wg[5] * r1[2]
                         + wg[6] * r2[0] + wg[7] * r2[1] + wg[8] * r2[2];
        float sig = 1.f / (1.f + __expf(-acc));
        outbB[(size_t)(h * Wn + w) * DI] = f2bf(acc * sig);
        r0[0] = r1[0]; r0[1] = r1[1]; r0[2] = r1[2];
        r1[0] = r2[0]; r1[1] = r2[1]; r1[2] = r2[2];
        if (h + 2 < Hn) { r2[0] = LDV(h + 2, w - 1); r2[1] = LDV(h + 2, w); r2[2] = LDV(h + 2, w + 1); }
        else { r2[0] = r2[1] = r2[2] = 0.f; }
    }
    #undef LDV
}

// ---------- kernel 3: projection GEMM via MFMA bf16 — 32-row tiles, grid 512, 2x2 waves ----------
__global__ __launch_bounds__(256) void k_proj(const unsigned short* __restrict__ xcB,
                                              const float* __restrict__ xpw,
                                              float* __restrict__ P) {
    __shared__ short sA[32][40];
    __shared__ short sW[160][40];
    int r0 = blockIdx.x * 32;
    int tid = threadIdx.x;
    int w = tid >> 6, lane = tid & 63;
    int ln15 = lane & 15, q8 = (lane >> 4) * 8;
    int wrh = w & 1;    // row half (16 rows)
    int wch = w >> 1;   // col half (5 ni tiles = 80 cols)
    f32x4 acc[5];
    #pragma unroll
    for (int i = 0; i < 5; ++i) acc[i] = f32x4{0.f, 0.f, 0.f, 0.f};
    for (int kk = 0; kk < 8; ++kk) {
        if (tid < 128) {
            int r = tid >> 2, cc = (tid & 3) * 8;
            *(bf16x8*)&sA[r][cc] =
                *(const bf16x8*)(xcB + (size_t)(r0 + r) * DI + kk * 32 + cc);
        }
        if (tid < 160) {
            const float* src = xpw + (size_t)tid * DI + kk * 32;
            #pragma unroll
            for (int j = 0; j < 8; ++j) {
                float4 v = *(const float4*)(src + j * 4);
                sW[tid][j * 4 + 0] = (short)f2bf(v.x);
                sW[tid][j * 4 + 1] = (short)f2bf(v.y);
                sW[tid][j * 4 + 2] = (short)f2bf(v.z);
                sW[tid][j * 4 + 3] = (short)f2bf(v.w);
            }
        }
        __syncthreads();
        bf16x8 a = *(bf16x8*)&sA[wrh * 16 + ln15][q8];
        #pragma unroll
        for (int ni = 0; ni < 5; ++ni) {
            bf16x8 bfr = *(bf16x8*)&sW[(wch * 5 + ni) * 16 + ln15][q8];
            acc[ni] = __builtin_amdgcn_mfma_f32_16x16x32_bf16(a, bfr, acc[ni], 0, 0, 0);
        }
        __syncthreads();
    }
    int rbase = r0 + wrh * 16 + (lane >> 4) * 4;
    #pragma unroll
    for (int ni = 0; ni < 5; ++ni)
        #pragma unroll
        for (int rr = 0; rr < 4; ++rr)
            P[(size_t)(rbase + rr) * 160 + (wch * 5 + ni) * 16 + ln15] = acc[ni][rr];
}

// ---------- scan step cores ----------
// Phase A single-step (R9 form): state chain only. Reads rec[0..24): dts(8) + B(16).
template <bool CHAIN>
__device__ __forceinline__ void sA_step(const float* __restrict__ rec, float u,
                                        const f32x2 wr2[4], float bias,
                                        const float* __restrict__ A_logs, int kd,
                                        f32x2 h2[8], float& sde) {
    float dtv = bias + dot8p(wr2, rec);
    float de, e1;
    softplus_e1(dtv, de, e1);
    float du = de * u;
    sde += de;
    f32x2 Ba[8];
    #pragma unroll
    for (int i = 0; i < 4; ++i) {
        f32x4 v = *(const f32x4*)(rec + 8 + i * 4);
        Ba[2 * i]     = f32x2{v.x, v.y};
        Ba[2 * i + 1] = f32x2{v.z, v.w};
    }
    f32x2 du2 = {du, du};
    if constexpr (CHAIN) {
        f32x2 pe[8];
        powpairs(e1, pe);
        #pragma unroll
        for (int j = 0; j < 8; ++j) {
            f32x2 t = du2 * Ba[j];
            h2[j] = pe[j] * h2[j] + t;
        }
    } else {
        #pragma unroll
        for (int j = 0; j < 8; ++j) {
            float A0 = -__expf(A_logs[(size_t)kd * 16 + 2 * j]);
            float A1 = -__expf(A_logs[(size_t)kd * 16 + 2 * j + 1]);
            f32x2 dec = {__expf(de * A0), __expf(de * A1)};
            f32x2 t = du2 * Ba[j];
            h2[j] = dec * h2[j] + t;
        }
    }
}
// Phase C pair compute (prefetched operands): full chains + two y outputs.
template <bool CHAIN>
__device__ __forceinline__ void sC_comp2(const f32x2 rd[4], const f32x2 Ba[8], const f32x2 Ca[8],
                                         float uA, float uB,
                                         const f32x2 wr2A[4], const f32x2 wr2B[4],
                                         float biasA, float biasB, float DvA, float DvB,
                                         const float* __restrict__ A_logs, int kdA, int kdB,
                                         f32x2 hA[8], f32x2 hB[8],
                                         float& yA, float& yB) {
    float dtvA = biasA + dotr(wr2A, rd);
    float dtvB = biasB + dotr(wr2B, rd);
    float deA, e1A, deB, e1B;
    softplus_e1(dtvA, deA, e1A);
    softplus_e1(dtvB, deB, e1B);
    float duA = deA * uA, duB = deB * uB;
    f32x2 duA2 = {duA, duA}, duB2 = {duB, duB};
    f32x2 yvA[2], yvB[2];
    yvA[0] = f32x2{DvA * uA, 0.f}; yvA[1] = f32x2{0.f, 0.f};
    yvB[0] = f32x2{DvB * uB, 0.f}; yvB[1] = f32x2{0.f, 0.f};
    if constexpr (CHAIN) {
        f32x2 peA[8], peB[8];
        powpairs(e1A, peA);
        powpairs(e1B, peB);
        #pragma unroll
        for (int j = 0; j < 8; ++j) {
            hA[j] = peA[j] * hA[j] + duA2 * Ba[j];
            hB[j] = peB[j] * hB[j] + duB2 * Ba[j];
            yvA[j & 1] += hA[j] * Ca[j];
            yvB[j & 1] += hB[j] * Ca[j];
        }
    } else {
        #pragma unroll
        for (int j = 0; j < 8; ++j) {
            float A0a = -__expf(A_logs[(size_t)kdA * 16 + 2 * j]);
            float A1a = -__expf(A_logs[(size_t)kdA * 16 + 2 * j + 1]);
            float A0b = -__expf(A_logs[(size_t)kdB * 16 + 2 * j]);
            float A1b = -__expf(A_logs[(size_t)kdB * 16 + 2 * j + 1]);
            f32x2 decA = {__expf(deA * A0a), __expf(deA * A1a)};
            f32x2 decB = {__expf(deB * A0b), __expf(deB * A1b)};
            hA[j] = decA * hA[j] + duA2 * Ba[j];
            hB[j] = decB * hB[j] + duB2 * Ba[j];
            yvA[j & 1] += hA[j] * Ca[j];
            yvB[j & 1] += hB[j] * Ca[j];
        }
    }
    f32x2 sA2 = yvA[0] + yvA[1];
    f32x2 sB2 = yvB[0] + yvB[1];
    yA = sA2.x + sA2.y;
    yB = sB2.x + sB2.y;
}

// ---------- kernel 4: phase A — per-chunk state summaries only (R9 structure, unpaired) ----------
// grid 2048 = 4b * 4k * 128c ; block 256 ; no LDS, no y output.
__global__ __launch_bounds__(256, 8) void k_scanA(const unsigned short* __restrict__ xcB,
                                                  const float* __restrict__ P,
                                                  const float* __restrict__ dtw,
                                                  const float* __restrict__ dtb,
                                                  const float* __restrict__ A_logs,
                                                  float* __restrict__ carrG,
                                                  unsigned short* __restrict__ carrH) {
    int bid = blockIdx.x;
    int c = bid & (NC - 1);
    int k = (bid >> 7) & 3;
    int b = bid >> 9;
    int tid = threadIdx.x;
    int kd = k * DI + tid;
    f32x2 wr2[4];
    load_wr2(dtw, kd, wr2);
    float bias = dtb[kd];
    bool ch = check_chain(A_logs, kd);
    f32x2 h2[8];
    #pragma unroll
    for (int j = 0; j < 8; ++j) h2[j] = f32x2{0.f, 0.f};
    float sde = 0.f;
    int t0 = c * CHUNK;
    int p0 = posk(k, t0), dp = posk(k, t0 + 1) - p0;
    const float* rec = P + ((size_t)b * LL + p0) * 160 + k * 40;
    const unsigned short* up = xcB + ((size_t)b * LL + p0) * DI + tid;
    long rs = (long)dp * 160, us = (long)dp * DI;
    if (ch) {
        for (int tt = 0; tt < CHUNK; ++tt) {
            sA_step<true>(rec, bf2f(*up), wr2, bias, A_logs, kd, h2, sde);
            rec += rs; up += us;
        }
    } else {
        for (int tt = 0; tt < CHUNK; ++tt) {
            sA_step<false>(rec, bf2f(*up), wr2, bias, A_logs, kd, h2, sde);
            rec += rs; up += us;
        }
    }
    // carries (chunk index in the direction's own scan order)
    carrG[((size_t)(b * Kn + k) * NC + c) * DI + tid] = sde;
    size_t hb = ((size_t)(b * Kn + k) * NC + c) * 16 * DI + tid;
    #pragma unroll
    for (int j = 0; j < 8; ++j) {
        carrH[hb + (size_t)(2 * j) * DI]     = f2bf(h2[j].x);
        carrH[hb + (size_t)(2 * j + 1) * DI] = f2bf(h2[j].y);
    }
}

// ---------- kernel 5: scan phase 2 — combine carries across chunks ----------
__global__ __launch_bounds__(256) void k_scan2(const float* __restrict__ carrG,
                                               const float* __restrict__ A_logs,
                                               unsigned short* __restrict__ carrH) {
    int gid = blockIdx.x * 256 + threadIdx.x;
    int d = gid & 255;
    int n = (gid >> 8) & 15;
    int bk = gid >> 12;
    int k = bk & 3;
    float Ac = -__expf(A_logs[(size_t)(k * DI + d) * 16 + n]);
    size_t gbase = (size_t)bk * NC * DI + d;
    size_t hbase = ((size_t)bk * NC * 16 + n) * DI + d;
    const size_t hs = (size_t)16 * DI;
    float hr = 0.f;
    #pragma unroll
    for (int g = 0; g < NC / 32; ++g) {
        float sv[32];
        unsigned short hvv[32];
        #pragma unroll
        for (int j = 0; j < 32; ++j) sv[j] = carrG[gbase + (size_t)(g * 32 + j) * DI];
        #pragma unroll
        for (int j = 0; j < 32; ++j) hvv[j] = carrH[hbase + (size_t)(g * 32 + j) * hs];
        #pragma unroll
        for (int j = 0; j < 32; ++j) {
            float a = __expf(Ac * sv[j]);
            float he = bf2f(hvv[j]);
            carrH[hbase + (size_t)(g * 32 + j) * hs] = f2bf(hr);
            hr = a * hr + he;
        }
    }
}

// ---------- kernel 6: phase C — full chain with combined h0, 2 d/thread + record prefetch ----------
// grid 2048 = 4b * 4k * 128c ; block 128 threads. Outputs per-direction:
// k=0 -> y0 (f32, row-major, = d_out), k=1 -> y1 (bf16, wh order),
// k=2 -> y2 (bf16, row-major), k=3 -> y3 (bf16, wh order)
__global__ __launch_bounds__(128, 4) void k_scanC(const unsigned short* __restrict__ xcB,
                                                  const float* __restrict__ P,
                                                  const float* __restrict__ dtw,
                                                  const float* __restrict__ dtb,
                                                  const float* __restrict__ A_logs,
                                                  const float* __restrict__ Ds,
                                                  const unsigned short* __restrict__ carrH,
                                                  float* __restrict__ y0,
                                                  unsigned short* __restrict__ y1,
                                                  unsigned short* __restrict__ y2,
                                                  unsigned short* __restrict__ y3) {
    int bid = blockIdx.x;
    int c = bid & (NC - 1);
    int k = (bid >> 7) & 3;
    int b = bid >> 9;
    int tid = threadIdx.x;          // 0..127
    int kdA = k * DI + tid, kdB = kdA + 128;
    f32x2 wr2A[4], wr2B[4];
    load_wr2(dtw, kdA, wr2A);
    load_wr2(dtw, kdB, wr2B);
    float biasA = dtb[kdA], biasB = dtb[kdB];
    float DvA = Ds[kdA], DvB = Ds[kdB];
    bool ch = check_chain(A_logs, kdA) && check_chain(A_logs, kdB);
    // h0 = prefix-combined incoming state for this chunk
    f32x2 hA[8], hB[8];
    size_t hb = ((size_t)(b * Kn + k) * NC + c) * 16 * DI + tid;
    #pragma unroll
    for (int j = 0; j < 8; ++j) {
        hA[j] = f32x2{bf2f(carrH[hb + (size_t)(2 * j) * DI]),
                      bf2f(carrH[hb + (size_t)(2 * j + 1) * DI])};
        hB[j] = f32x2{bf2f(carrH[hb + 128 + (size_t)(2 * j) * DI]),
                      bf2f(carrH[hb + 128 + (size_t)(2 * j + 1) * DI])};
    }
    int t0 = c * CHUNK;
    int p0 = posk(k, t0), dp = posk(k, t0 + 1) - p0;
    const float* rec = P + ((size_t)b * LL + p0) * 160 + k * 40;
    const unsigned short* up = xcB + ((size_t)b * LL + p0) * DI + tid;
    long rs = (long)dp * 160, us = (long)dp * DI;
    // output stream (block-uniform selection); chain B is +128 elements
    bool rev = (k >= 2);
    bool f32o = (k == 0);
    size_t i0 = rev ? (size_t)(LL - 1 - t0) : (size_t)t0;
    long ystepB, boff;
    char* yp;
    if (k == 0)      { yp = (char*)(y0 + ((size_t)b * LL + i0) * DI + tid); ystepB = (long)DI * 4; boff = 128 * 4; }
    else if (k == 1) { yp = (char*)(y1 + ((size_t)b * LL + i0) * DI + tid); ystepB = (long)DI * 2; boff = 128 * 2; }
    else if (k == 2) { yp = (char*)(y2 + ((size_t)b * LL + i0) * DI + tid); ystepB = -(long)DI * 2; boff = 128 * 2; }
    else             { yp = (char*)(y3 + ((size_t)b * LL + i0) * DI + tid); ystepB = -(long)DI * 2; boff = 128 * 2; }
    // software pipeline: record + u double-buffered in registers (statically indexed).
    // One-past-end prefetch on the last iteration stays inside the workspace for all
    // four directions (bounded above by y buffers, below by xcB) -- values unused.
    f32x2 rd[4], Ba[8], Ca[8];
    loadC_rec(rec, rd, Ba, Ca);
    float uA = bf2f(up[0]), uB = bf2f(up[128]);
    if (ch) {
        for (int tt = 0; tt < CHUNK; ++tt) {
            f32x2 rdn[4], Ban[8], Can[8];
            loadC_rec(rec + rs, rdn, Ban, Can);
            float uAn = bf2f(up[us]), uBn = bf2f(up[us + 128]);
            float yA, yB;
            sC_comp2<true>(rd, Ba, Ca, uA, uB, wr2A, wr2B, biasA, biasB,
                           DvA, DvB, A_logs, kdA, kdB, hA, hB, yA, yB);
            if (f32o) { *(float*)yp = yA; *(float*)(yp + boff) = yB; }
            else      { *(unsigned short*)yp = f2bf(yA); *(unsigned short*)(yp + boff) = f2bf(yB); }
            yp += ystepB;
            rec += rs; up += us;
            #pragma unroll
            for (int j = 0; j < 4; ++j) rd[j] = rdn[j];
            #pragma unroll
            for (int j = 0; j < 8; ++j) { Ba[j] = Ban[j]; Ca[j] = Can[j]; }
            uA = uAn; uB = uBn;
        }
    } else {
        for (int tt = 0; tt < CHUNK; ++tt) {
            f32x2 rdn[4], Ban[8], Can[8];
            loadC_rec(rec + rs, rdn, Ban, Can);
            float uAn = bf2f(up[us]), uBn = bf2f(up[us + 128]);
            float yA, yB;
            sC_comp2<false>(rd, Ba, Ca, uA, uB, wr2A, wr2B, biasA, biasB,
                            DvA, DvB, A_logs, kdA, kdB, hA, hB, yA, yB);
            if (f32o) { *(float*)yp = yA; *(float*)(yp + boff) = yB; }
            else      { *(unsigned short*)yp = f2bf(yA); *(unsigned short*)(yp + boff) = f2bf(yB); }
            yp += ystepB;
            rec += rs; up += us;
            #pragma unroll
            for (int j = 0; j < 4; ++j) rd[j] = rdn[j];
            #pragma unroll
            for (int j = 0; j < 8; ++j) { Ba[j] = Ban[j]; Ca[j] = Can[j]; }
            uA = uAn; uB = uBn;
        }
    }
}

// ---------- kernel 7: LayerNorm — combine 4 direction buffers, one wave per row ----------
// grid 4096 = 16384 rows / 4 rows per block ; block 256 = 4 waves
__global__ __launch_bounds__(256) void k_ln(float* __restrict__ y,
                                            const unsigned short* __restrict__ y1,
                                            const unsigned short* __restrict__ y2,
                                            const unsigned short* __restrict__ y3,
                                            const float* __restrict__ gamma,
                                            const float* __restrict__ beta) {
    int tid = threadIdx.x;
    int w = tid >> 6, lane = tid & 63;
    int r = blockIdx.x * 4 + w;
    int b = r >> 12;
    int pos = r & 4095;
    int q = ((pos & 63) << 6) | (pos >> 6);   // y1/y3 are stored in wh-scan order
    float4 vy = *(const float4*)(y + (size_t)r * DI + lane * 4);
    ushort4v v2 = *(const ushort4v*)(y2 + (size_t)r * DI + lane * 4);
    ushort4v v1 = *(const ushort4v*)(y1 + ((size_t)b * LL + q) * DI + lane * 4);
    ushort4v v3 = *(const ushort4v*)(y3 + ((size_t)b * LL + q) * DI + lane * 4);
    float v0 = vy.x + bf2f(v2.x) + bf2f(v1.x) + bf2f(v3.x);
    float vv1 = vy.y + bf2f(v2.y) + bf2f(v1.y) + bf2f(v3.y);
    float vv2 = vy.z + bf2f(v2.z) + bf2f(v1.z) + bf2f(v3.z);
    float vv3 = vy.w + bf2f(v2.w) + bf2f(v1.w) + bf2f(v3.w);
    float a = (v0 + vv1) + (vv2 + vv3);
    float bsq = (v0 * v0 + vv1 * vv1) + (vv2 * vv2 + vv3 * vv3);
    #pragma unroll
    for (int off = 32; off; off >>= 1) {
        a += __shfl_xor(a, off);
        bsq += __shfl_xor(bsq, off);
    }
    float mu = a * (1.f / 256.f);
    float var = bsq * (1.f / 256.f) - mu * mu;
    float rs = rsqrtf(var + 1e-5f);
    float4 gm = *(const float4*)(gamma + lane * 4);
    float4 bt = *(const float4*)(beta + lane * 4);
    float4 o;
    o.x = (v0 - mu) * rs * gm.x + bt.x;
    o.y = (vv1 - mu) * rs * gm.y + bt.y;
    o.z = (vv2 - mu) * rs * gm.z + bt.z;
    o.w = (vv3 - mu) * rs * gm.w + bt.w;
    *(float4*)(y + (size_t)r * DI + lane * 4) = o;
}

// ---------- launch ----------
extern "C" void kernel_launch(void* const* d_in, const int* in_sizes, int n_in,
                              void* d_out, int out_size, void* d_ws, size_t ws_size,
                              hipStream_t stream) {
    const float* x    = (const float*)d_in[0];
    const float* ipw  = (const float*)d_in[1];
    const float* cw   = (const float*)d_in[2];
    const float* cb   = (const float*)d_in[3];
    const float* xpw  = (const float*)d_in[4];
    const float* dtw  = (const float*)d_in[5];
    const float* dtb  = (const float*)d_in[6];
    const float* alog = (const float*)d_in[7];
    const float* Ds   = (const float*)d_in[8];
    const float* gam  = (const float*)d_in[9];
    const float* bet  = (const float*)d_in[10];

    // ws layout (bytes):
    //   [0, 16777216)           carrH (bf16) -- aliases xls_pre (in_proj out, dead after conv)
    //   [16777216, 18874368)    carrG (fp32)
    //   [18874368, 27262976)    xcB   (bf16 B*L*DI)
    //   [27262976, 37748736)    P     (fp32 B*L*160, image order: [k*40: dts|B|C])
    //   [37748736, 46137344)    y1    (bf16 B*L*DI, dir1 in wh-scan order)
    //   [46137344, 54525952)    y2    (bf16 B*L*DI, dir2 row-major)
    //   [54525952, 62914560)    y3    (bf16 B*L*DI, dir3 wh-scan order)
    const size_t WS_NEED = 62914560;
    if (ws_size < WS_NEED) return;

    char* ws = (char*)d_ws;
    unsigned short* carrH = (unsigned short*)(ws + 0);
    float* carrG   = (float*)(ws + 16777216);
    float* xls_pre = (float*)(ws + 0);
    unsigned short* xcB = (unsigned short*)(ws + 18874368);
    float* P       = (float*)(ws + 27262976);
    unsigned short* y1 = (unsigned short*)(ws + 37748736);
    unsigned short* y2 = (unsigned short*)(ws + 46137344);
    unsigned short* y3 = (unsigned short*)(ws + 54525952);
    float* y       = (float*)d_out;

    k_inproj<<<1024,  256, 0, stream>>>(x, ipw, xls_pre);
    k_conv  <<<1024,  256, 0, stream>>>(xls_pre, cw, cb, xcB);
    k_proj  <<<512,   256, 0, stream>>>(xcB, xpw, P);
    k_scanA <<<2048,  256, 0, stream>>>(xcB, P, dtw, dtb, alog, carrG, carrH);
    k_scan2 <<<256,   256, 0, stream>>>(carrG, alog, carrH);
    k_scanC <<<2048,  128, 0, stream>>>(xcB, P, dtw, dtb, alog, Ds, carrH, y, y1, y2, y3);
    k_ln    <<<4096,  256, 0, stream>>>(y, y1, y2, y3, gam, bet);
}

// Round 15
// 210.614 us; speedup vs baseline: 1.0647x; 1.0204x over previous
//
#include <hip/hip_runtime.h>

constexpr int Bn = 4;
constexpr int Hn = 64;
constexpr int Wn = 64;
constexpr int LL = Hn * Wn;     // 4096
constexpr int DM = 128;
constexpr int DI = 256;
constexpr int Nn = 16;
constexpr int Rn = 8;
constexpr int Kn = 4;
constexpr int NC = 128;         // chunks per (b,k) scan  -- proven sweet spot (R0/R1)
constexpr int CHUNK = LL / NC;  // 32

using bf16x8 = __attribute__((ext_vector_type(8))) short;
using f32x4  = __attribute__((ext_vector_type(4))) float;
using f32x2  = __attribute__((ext_vector_type(2))) float;
using ushort4v = __attribute__((ext_vector_type(4))) unsigned short;

// ---------- helpers ----------
__device__ __forceinline__ float bf2f(unsigned short s) {
    return __uint_as_float(((unsigned int)s) << 16);
}
__device__ __forceinline__ unsigned short f2bf(float f) {
    unsigned int u = __float_as_uint(f);
    u += 0x7FFFu + ((u >> 16) & 1u);   // RNE
    return (unsigned short)(u >> 16);
}
__device__ __forceinline__ float softplus_f(float x) {
    if (x > 20.f) return x;
    return __logf(1.f + __expf(x));
}
// de = softplus(dtv), e1 = exp(-de) == 1/(1+exp(dtv))
__device__ __forceinline__ void softplus_e1(float dtv, float& de, float& e1) {
    float E = __expf(dtv);
    de = (dtv > 20.f) ? dtv : __logf(1.f + E);
    e1 = __builtin_amdgcn_rcpf(1.f + E);
}
// scan-order index t -> image position (row-major h*64+w)
__device__ __forceinline__ int posk(int k, int t) {
    int q = (k >= 2) ? (LL - 1 - t) : t;
    return (k & 1) ? (((q & 63) << 6) | (q >> 6)) : q;
}
// packed dot8: wr pre-packed as 4 x f32x2; rec 8B-aligned (k*40 floats = 160B)
__device__ __forceinline__ float dot8p(const f32x2 wr2[4], const float* rec) {
    const f32x2* r2 = (const f32x2*)rec;
    f32x2 s = wr2[0] * r2[0];
    s += wr2[1] * r2[1];
    s += wr2[2] * r2[2];
    s += wr2[3] * r2[3];
    return s.x + s.y;
}
// dot of pre-packed weight pairs with pre-loaded record pairs
__device__ __forceinline__ float dotr(const f32x2 wr2[4], const f32x2 rd[4]) {
    f32x2 s = wr2[0] * rd[0];
    s += wr2[1] * rd[1];
    s += wr2[2] * rd[2];
    s += wr2[3] * rd[3];
    return s.x + s.y;
}
__device__ __forceinline__ void load_wr2(const float* __restrict__ dtw, int kd, f32x2 wr2[4]) {
    f32x4 v0 = *(const f32x4*)(dtw + (size_t)kd * 8);
    f32x4 v1 = *(const f32x4*)(dtw + (size_t)kd * 8 + 4);
    wr2[0] = f32x2{v0.x, v0.y};
    wr2[1] = f32x2{v0.z, v0.w};
    wr2[2] = f32x2{v1.x, v1.y};
    wr2[3] = f32x2{v1.z, v1.w};
}
// pe[j] = {e1^(2j+1), e1^(2j+2)} for j=0..7, shallow independent tree (pk-fp32 friendly)
__device__ __forceinline__ void powpairs(float e1, f32x2 pe[8]) {
    float e2s = e1 * e1, e4s = e2s * e2s, e8s = e4s * e4s;
    f32x2 E2 = {e2s, e2s}, E4 = {e4s, e4s}, E8 = {e8s, e8s};
    pe[0] = f32x2{e1, e2s};
    pe[1] = pe[0] * E2;
    pe[2] = pe[0] * E4;
    pe[3] = pe[1] * E4;
    pe[4] = pe[0] * E8;
    pe[5] = pe[1] * E8;
    pe[6] = pe[2] * E8;
    pe[7] = pe[3] * E8;
}
// true iff -exp(A_logs[kd][n]) == -(n+1)  (A_logs = log(1..16) structure)
__device__ __forceinline__ bool check_chain(const float* __restrict__ A_logs, int kd) {
    float a0 = -__expf(A_logs[(size_t)kd * 16]);
    bool ok = fabsf(a0 + 1.f) < 1e-6f;
    #pragma unroll
    for (int n = 1; n < 16; ++n) {
        float an = -__expf(A_logs[(size_t)kd * 16 + n]);
        ok = ok && (fabsf(an - (float)(n + 1) * a0) <= 1e-4f * fabsf(an));
    }
    return ok;
}

// ---------- kernel 1: in_proj GEMM via MFMA bf16 — 64x64 tiles, grid 1024 (4 blocks/CU) ----------
__global__ __launch_bounds__(256) void k_inproj(const float* __restrict__ x,
                                                const float* __restrict__ wp,
                                                float* __restrict__ out) {
    __shared__ short sA[64][40];
    __shared__ short sW[64][40];
    int bid = blockIdx.x;
    int r0 = (bid >> 2) * 64;       // row tile (0..255)
    int c0 = (bid & 3) * 64;        // col group (0..3)
    int tid = threadIdx.x;
    int w = tid >> 6, lane = tid & 63;
    int ln15 = lane & 15, q8 = (lane >> 4) * 8;
    f32x4 acc[4];
    #pragma unroll
    for (int i = 0; i < 4; ++i) acc[i] = f32x4{0.f, 0.f, 0.f, 0.f};
    int r = tid >> 2, cc = (tid & 3) * 8;
    for (int kk = 0; kk < 4; ++kk) {
        {
            const float* src = x + (size_t)(r0 + r) * DM + kk * 32 + cc;
            float4 v0 = *(const float4*)src;
            float4 v1 = *(const float4*)(src + 4);
            bf16x8 s;
            s[0] = (short)f2bf(v0.x); s[1] = (short)f2bf(v0.y);
            s[2] = (short)f2bf(v0.z); s[3] = (short)f2bf(v0.w);
            s[4] = (short)f2bf(v1.x); s[5] = (short)f2bf(v1.y);
            s[6] = (short)f2bf(v1.z); s[7] = (short)f2bf(v1.w);
            *(bf16x8*)&sA[r][cc] = s;
        }
        {
            const float* src = wp + (size_t)(c0 + r) * DM + kk * 32 + cc;
            float4 v0 = *(const float4*)src;
            float4 v1 = *(const float4*)(src + 4);
            bf16x8 s;
            s[0] = (short)f2bf(v0.x); s[1] = (short)f2bf(v0.y);
            s[2] = (short)f2bf(v0.z); s[3] = (short)f2bf(v0.w);
            s[4] = (short)f2bf(v1.x); s[5] = (short)f2bf(v1.y);
            s[6] = (short)f2bf(v1.z); s[7] = (short)f2bf(v1.w);
            *(bf16x8*)&sW[r][cc] = s;
        }
        __syncthreads();
        bf16x8 a = *(bf16x8*)&sA[w * 16 + ln15][q8];
        #pragma unroll
        for (int ni = 0; ni < 4; ++ni) {
            bf16x8 bfr = *(bf16x8*)&sW[ni * 16 + ln15][q8];
            acc[ni] = __builtin_amdgcn_mfma_f32_16x16x32_bf16(a, bfr, acc[ni], 0, 0, 0);
        }
        __syncthreads();
    }
    int rbase = r0 + w * 16 + (lane >> 4) * 4;
    #pragma unroll
    for (int ni = 0; ni < 4; ++ni)
        #pragma unroll
        for (int rr = 0; rr < 4; ++rr)
            out[(size_t)(rbase + rr) * DI + c0 + ni * 16 + ln15] = acc[ni][rr];
}

// ---------- kernel 2: depthwise 3x3 conv + bias + SiLU — 8-row bands, grid 2048 (8 blocks/CU) ----------
__global__ __launch_bounds__(256) void k_conv(const float* __restrict__ xin,
                                              const float* __restrict__ cw,
                                              const float* __restrict__ cb,
                                              unsigned short* __restrict__ xoutB) {
    int bid = blockIdx.x;
    int band = bid & 7;
    int wblk = (bid >> 3) & 15;
    int dblk = (bid >> 7) & 3;
    int b    = bid >> 9;
    int tid = threadIdx.x;
    int d = dblk * 64 + (tid & 63);
    int w = wblk * 4 + (tid >> 6);
    const float* inb = xin + (size_t)b * LL * DI + d;
    unsigned short* outbB = xoutB + (size_t)b * LL * DI + d;
    float wg[9];
    #pragma unroll
    for (int i = 0; i < 9; ++i) wg[i] = cw[d * 9 + i];
    float bias = cb[d];
    #define LDV(hhh, www) ((((www) >= 0) && ((www) < Wn)) ? inb[(size_t)((hhh) * Wn + (www)) * DI] : 0.f)
    int hs = band * 8;
    float r0[3], r1[3], r2[3];
    if (hs == 0) { r0[0] = r0[1] = r0[2] = 0.f; }
    else { r0[0] = LDV(hs - 1, w - 1); r0[1] = LDV(hs - 1, w); r0[2] = LDV(hs - 1, w + 1); }
    r1[0] = LDV(hs, w - 1); r1[1] = LDV(hs, w); r1[2] = LDV(hs, w + 1);
    r2[0] = LDV(hs + 1, w - 1); r2[1] = LDV(hs + 1, w); r2[2] = LDV(hs + 1, w + 1);
    for (int h = hs; h < hs + 8; ++h) {
        float acc = bias + wg[0] * r0[0] + wg[1] * r0[1] + wg[2] * r0[2]
                         + wg[3] * r1[0] + wg[4] * r1[1] + wg[5] * r1[2]
                         + wg[6] * r2[0] + wg[7] * r2[1] + wg[8] * r2[2];
        float sig = 1.f / (1.f + __expf(-acc));
        outbB[(size_t)(h * Wn + w) * DI] = f2bf(acc * sig);
        r0[0] = r1[0]; r0[1] = r1[1]; r0[2] = r1[2];
        r1[0] = r2[0]; r1[1] = r2[1]; r1[2] = r2[2];
        if (h + 2 < Hn) { r2[0] = LDV(h + 2, w - 1); r2[1] = LDV(h + 2, w); r2[2] = LDV(h + 2, w + 1); }
        else { r2[0] = r2[1] = r2[2] = 0.f; }
    }
    #undef LDV
}

// ---------- kernel 3: projection GEMM via MFMA bf16 — 32-row tiles, grid 512, 2x2 waves ----------
__global__ __launch_bounds__(256) void k_proj(const unsigned short* __restrict__ xcB,
                                              const float* __restrict__ xpw,
                                              float* __restrict__ P) {
    __shared__ short sA[32][40];
    __shared__ short sW[160][40];
    int r0 = blockIdx.x * 32;
    int tid = threadIdx.x;
    int w = tid >> 6, lane = tid & 63;
    int ln15 = lane & 15, q8 = (lane >> 4) * 8;
    int wrh = w & 1;    // row half (16 rows)
    int wch = w >> 1;   // col half (5 ni tiles = 80 cols)
    f32x4 acc[5];
    #pragma unroll
    for (int i = 0; i < 5; ++i) acc[i] = f32x4{0.f, 0.f, 0.f, 0.f};
    for (int kk = 0; kk < 8; ++kk) {
        if (tid < 128) {
            int r = tid >> 2, cc = (tid & 3) * 8;
            *(bf16x8*)&sA[r][cc] =
                *(const bf16x8*)(xcB + (size_t)(r0 + r) * DI + kk * 32 + cc);
        }
        if (tid < 160) {
            const float* src = xpw + (size_t)tid * DI + kk * 32;
            #pragma unroll
            for (int j = 0; j < 8; ++j) {
                float4 v = *(const float4*)(src + j * 4);
                sW[tid][j * 4 + 0] = (short)f2bf(v.x);
                sW[tid][j * 4 + 1] = (short)f2bf(v.y);
                sW[tid][j * 4 + 2] = (short)f2bf(v.z);
                sW[tid][j * 4 + 3] = (short)f2bf(v.w);
            }
        }
        __syncthreads();
        bf16x8 a = *(bf16x8*)&sA[wrh * 16 + ln15][q8];
        #pragma unroll
        for (int ni = 0; ni < 5; ++ni) {
            bf16x8 bfr = *(bf16x8*)&sW[(wch * 5 + ni) * 16 + ln15][q8];
            acc[ni] = __builtin_amdgcn_mfma_f32_16x16x32_bf16(a, bfr, acc[ni], 0, 0, 0);
        }
        __syncthreads();
    }
    int rbase = r0 + wrh * 16 + (lane >> 4) * 4;
    #pragma unroll
    for (int ni = 0; ni < 5; ++ni)
        #pragma unroll
        for (int rr = 0; rr < 4; ++rr)
            P[(size_t)(rbase + rr) * 160 + (wch * 5 + ni) * 16 + ln15] = acc[ni][rr];
}

// ---------- scan step cores ----------
// Phase A single-step (R9 form): state chain only. Reads rec[0..24): dts(8) + B(16).
template <bool CHAIN>
__device__ __forceinline__ void sA_step(const float* __restrict__ rec, float u,
                                        const f32x2 wr2[4], float bias,
                                        const float* __restrict__ A_logs, int kd,
                                        f32x2 h2[8], float& sde) {
    float dtv = bias + dot8p(wr2, rec);
    float de, e1;
    softplus_e1(dtv, de, e1);
    float du = de * u;
    sde += de;
    f32x2 Ba[8];
    #pragma unroll
    for (int i = 0; i < 4; ++i) {
        f32x4 v = *(const f32x4*)(rec + 8 + i * 4);
        Ba[2 * i]     = f32x2{v.x, v.y};
        Ba[2 * i + 1] = f32x2{v.z, v.w};
    }
    f32x2 du2 = {du, du};
    if constexpr (CHAIN) {
        f32x2 pe[8];
        powpairs(e1, pe);
        #pragma unroll
        for (int j = 0; j < 8; ++j) {
            f32x2 t = du2 * Ba[j];
            h2[j] = pe[j] * h2[j] + t;
        }
    } else {
        #pragma unroll
        for (int j = 0; j < 8; ++j) {
            float A0 = -__expf(A_logs[(size_t)kd * 16 + 2 * j]);
            float A1 = -__expf(A_logs[(size_t)kd * 16 + 2 * j + 1]);
            f32x2 dec = {__expf(de * A0), __expf(de * A1)};
            f32x2 t = du2 * Ba[j];
            h2[j] = dec * h2[j] + t;
        }
    }
}
// Phase C pair-step (R10 form): full chains + two y outputs. Record (40 floats) loaded once.
template <bool CHAIN>
__device__ __forceinline__ void sC_step2(const float* __restrict__ rec, float uA, float uB,
                                         const f32x2 wr2A[4], const f32x2 wr2B[4],
                                         float biasA, float biasB, float DvA, float DvB,
                                         const float* __restrict__ A_logs, int kdA, int kdB,
                                         f32x2 hA[8], f32x2 hB[8],
                                         float& yA, float& yB) {
    f32x2 rd[4];
    {
        const f32x2* r2 = (const f32x2*)rec;
        rd[0] = r2[0]; rd[1] = r2[1]; rd[2] = r2[2]; rd[3] = r2[3];
    }
    f32x2 Ba[8], Ca[8];
    #pragma unroll
    for (int i = 0; i < 4; ++i) {
        f32x4 v = *(const f32x4*)(rec + 8 + i * 4);
        Ba[2 * i]     = f32x2{v.x, v.y};
        Ba[2 * i + 1] = f32x2{v.z, v.w};
        f32x4 w = *(const f32x4*)(rec + 24 + i * 4);
        Ca[2 * i]     = f32x2{w.x, w.y};
        Ca[2 * i + 1] = f32x2{w.z, w.w};
    }
    float dtvA = biasA + dotr(wr2A, rd);
    float dtvB = biasB + dotr(wr2B, rd);
    float deA, e1A, deB, e1B;
    softplus_e1(dtvA, deA, e1A);
    softplus_e1(dtvB, deB, e1B);
    float duA = deA * uA, duB = deB * uB;
    f32x2 duA2 = {duA, duA}, duB2 = {duB, duB};
    f32x2 yvA[2], yvB[2];
    yvA[0] = f32x2{DvA * uA, 0.f}; yvA[1] = f32x2{0.f, 0.f};
    yvB[0] = f32x2{DvB * uB, 0.f}; yvB[1] = f32x2{0.f, 0.f};
    if constexpr (CHAIN) {
        f32x2 peA[8], peB[8];
        powpairs(e1A, peA);
        powpairs(e1B, peB);
        #pragma unroll
        for (int j = 0; j < 8; ++j) {
            hA[j] = peA[j] * hA[j] + duA2 * Ba[j];
            hB[j] = peB[j] * hB[j] + duB2 * Ba[j];
            yvA[j & 1] += hA[j] * Ca[j];
            yvB[j & 1] += hB[j] * Ca[j];
        }
    } else {
        #pragma unroll
        for (int j = 0; j < 8; ++j) {
            float A0a = -__expf(A_logs[(size_t)kdA * 16 + 2 * j]);
            float A1a = -__expf(A_logs[(size_t)kdA * 16 + 2 * j + 1]);
            float A0b = -__expf(A_logs[(size_t)kdB * 16 + 2 * j]);
            float A1b = -__expf(A_logs[(size_t)kdB * 16 + 2 * j + 1]);
            f32x2 decA = {__expf(deA * A0a), __expf(deA * A1a)};
            f32x2 decB = {__expf(deB * A0b), __expf(deB * A1b)};
            hA[j] = decA * hA[j] + duA2 * Ba[j];
            hB[j] = decB * hB[j] + duB2 * Ba[j];
            yvA[j & 1] += hA[j] * Ca[j];
            yvB[j & 1] += hB[j] * Ca[j];
        }
    }
    f32x2 sA2 = yvA[0] + yvA[1];
    f32x2 sB2 = yvB[0] + yvB[1];
    yA = sA2.x + sA2.y;
    yB = sB2.x + sB2.y;
}

// ---------- kernel 4: phase A — per-chunk state summaries only (R9 structure, unpaired) ----------
// grid 2048 = 4b * 4k * 128c ; block 256 ; no LDS, no y output.
__global__ __launch_bounds__(256, 8) void k_scanA(const unsigned short* __restrict__ xcB,
                                                  const float* __restrict__ P,
                                                  const float* __restrict__ dtw,
                                                  const float* __restrict__ dtb,
                                                  const float* __restrict__ A_logs,
                                                  float* __restrict__ carrG,
                                                  unsigned short* __restrict__ carrH) {
    int bid = blockIdx.x;
    int c = bid & (NC - 1);
    int k = (bid >> 7) & 3;
    int b = bid >> 9;
    int tid = threadIdx.x;
    int kd = k * DI + tid;
    f32x2 wr2[4];
    load_wr2(dtw, kd, wr2);
    float bias = dtb[kd];
    bool ch = check_chain(A_logs, kd);
    f32x2 h2[8];
    #pragma unroll
    for (int j = 0; j < 8; ++j) h2[j] = f32x2{0.f, 0.f};
    float sde = 0.f;
    int t0 = c * CHUNK;
    int p0 = posk(k, t0), dp = posk(k, t0 + 1) - p0;
    const float* rec = P + ((size_t)b * LL + p0) * 160 + k * 40;
    const unsigned short* up = xcB + ((size_t)b * LL + p0) * DI + tid;
    long rs = (long)dp * 160, us = (long)dp * DI;
    if (ch) {
        for (int tt = 0; tt < CHUNK; ++tt) {
            sA_step<true>(rec, bf2f(*up), wr2, bias, A_logs, kd, h2, sde);
            rec += rs; up += us;
        }
    } else {
        for (int tt = 0; tt < CHUNK; ++tt) {
            sA_step<false>(rec, bf2f(*up), wr2, bias, A_logs, kd, h2, sde);
            rec += rs; up += us;
        }
    }
    // carries (chunk index in the direction's own scan order)
    carrG[((size_t)(b * Kn + k) * NC + c) * DI + tid] = sde;
    size_t hb = ((size_t)(b * Kn + k) * NC + c) * 16 * DI + tid;
    #pragma unroll
    for (int j = 0; j < 8; ++j) {
        carrH[hb + (size_t)(2 * j) * DI]     = f2bf(h2[j].x);
        carrH[hb + (size_t)(2 * j + 1) * DI] = f2bf(h2[j].y);
    }
}

// ---------- kernel 5: scan phase 2 — combine carries across chunks ----------
__global__ __launch_bounds__(256) void k_scan2(const float* __restrict__ carrG,
                                               const float* __restrict__ A_logs,
                                               unsigned short* __restrict__ carrH) {
    int gid = blockIdx.x * 256 + threadIdx.x;
    int d = gid & 255;
    int n = (gid >> 8) & 15;
    int bk = gid >> 12;
    int k = bk & 3;
    float Ac = -__expf(A_logs[(size_t)(k * DI + d) * 16 + n]);
    size_t gbase = (size_t)bk * NC * DI + d;
    size_t hbase = ((size_t)bk * NC * 16 + n) * DI + d;
    const size_t hs = (size_t)16 * DI;
    float hr = 0.f;
    #pragma unroll
    for (int g = 0; g < NC / 32; ++g) {
        float sv[32];
        unsigned short hvv[32];
        #pragma unroll
        for (int j = 0; j < 32; ++j) sv[j] = carrG[gbase + (size_t)(g * 32 + j) * DI];
        #pragma unroll
        for (int j = 0; j < 32; ++j) hvv[j] = carrH[hbase + (size_t)(g * 32 + j) * hs];
        #pragma unroll
        for (int j = 0; j < 32; ++j) {
            float a = __expf(Ac * sv[j]);
            float he = bf2f(hvv[j]);
            carrH[hbase + (size_t)(g * 32 + j) * hs] = f2bf(hr);
            hr = a * hr + he;
        }
    }
}

// ---------- kernel 6: phase C — full chain with combined h0, 2 d/thread (R10/R11 structure) ----------
// grid 2048 = 4b * 4k * 128c ; block 128 threads. Outputs per-direction:
// k=0 -> y0 (f32, row-major, = d_out), k=1 -> y1 (bf16, wh order),
// k=2 -> y2 (bf16, row-major), k=3 -> y3 (bf16, wh order)
__global__ __launch_bounds__(128, 4) void k_scanC(const unsigned short* __restrict__ xcB,
                                                  const float* __restrict__ P,
                                                  const float* __restrict__ dtw,
                                                  const float* __restrict__ dtb,
                                                  const float* __restrict__ A_logs,
                                                  const float* __restrict__ Ds,
                                                  const unsigned short* __restrict__ carrH,
                                                  float* __restrict__ y0,
                                                  unsigned short* __restrict__ y1,
                                                  unsigned short* __restrict__ y2,
                                                  unsigned short* __restrict__ y3) {
    int bid = blockIdx.x;
    int c = bid & (NC - 1);
    int k = (bid >> 7) & 3;
    int b = bid >> 9;
    int tid = threadIdx.x;          // 0..127
    int kdA = k * DI + tid, kdB = kdA + 128;
    f32x2 wr2A[4], wr2B[4];
    load_wr2(dtw, kdA, wr2A);
    load_wr2(dtw, kdB, wr2B);
    float biasA = dtb[kdA], biasB = dtb[kdB];
    float DvA = Ds[kdA], DvB = Ds[kdB];
    bool ch = check_chain(A_logs, kdA) && check_chain(A_logs, kdB);
    // h0 = prefix-combined incoming state for this chunk
    f32x2 hA[8], hB[8];
    size_t hb = ((size_t)(b * Kn + k) * NC + c) * 16 * DI + tid;
    #pragma unroll
    for (int j = 0; j < 8; ++j) {
        hA[j] = f32x2{bf2f(carrH[hb + (size_t)(2 * j) * DI]),
                      bf2f(carrH[hb + (size_t)(2 * j + 1) * DI])};
        hB[j] = f32x2{bf2f(carrH[hb + 128 + (size_t)(2 * j) * DI]),
                      bf2f(carrH[hb + 128 + (size_t)(2 * j + 1) * DI])};
    }
    int t0 = c * CHUNK;
    int p0 = posk(k, t0), dp = posk(k, t0 + 1) - p0;
    const float* rec = P + ((size_t)b * LL + p0) * 160 + k * 40;
    const unsigned short* up = xcB + ((size_t)b * LL + p0) * DI + tid;
    long rs = (long)dp * 160, us = (long)dp * DI;
    // output stream (block-uniform selection); chain B is +128 elements
    bool rev = (k >= 2);
    bool f32o = (k == 0);
    size_t i0 = rev ? (size_t)(LL - 1 - t0) : (size_t)t0;
    long ystepB, boff;
    char* yp;
    if (k == 0)      { yp = (char*)(y0 + ((size_t)b * LL + i0) * DI + tid); ystepB = (long)DI * 4; boff = 128 * 4; }
    else if (k == 1) { yp = (char*)(y1 + ((size_t)b * LL + i0) * DI + tid); ystepB = (long)DI * 2; boff = 128 * 2; }
    else if (k == 2) { yp = (char*)(y2 + ((size_t)b * LL + i0) * DI + tid); ystepB = -(long)DI * 2; boff = 128 * 2; }
    else             { yp = (char*)(y3 + ((size_t)b * LL + i0) * DI + tid); ystepB = -(long)DI * 2; boff = 128 * 2; }
    if (ch) {
        for (int tt = 0; tt < CHUNK; ++tt) {
            float yA, yB;
            sC_step2<true>(rec, bf2f(up[0]), bf2f(up[128]), wr2A, wr2B, biasA, biasB,
                           DvA, DvB, A_logs, kdA, kdB, hA, hB, yA, yB);
            rec += rs; up += us;
            if (f32o) { *(float*)yp = yA; *(float*)(yp + boff) = yB; }
            else      { *(unsigned short*)yp = f2bf(yA); *(unsigned short*)(yp + boff) = f2bf(yB); }
            yp += ystepB;
        }
    } else {
        for (int tt = 0; tt < CHUNK; ++tt) {
            float yA, yB;
            sC_step2<false>(rec, bf2f(up[0]), bf2f(up[128]), wr2A, wr2B, biasA, biasB,
                            DvA, DvB, A_logs, kdA, kdB, hA, hB, yA, yB);
            rec += rs; up += us;
            if (f32o) { *(float*)yp = yA; *(float*)(yp + boff) = yB; }
            else      { *(unsigned short*)yp = f2bf(yA); *(unsigned short*)(yp + boff) = f2bf(yB); }
            yp += ystepB;
        }
    }
}

// ---------- kernel 7: LayerNorm — combine 4 direction buffers, one wave per row ----------
// grid 4096 = 16384 rows / 4 rows per block ; block 256 = 4 waves
__global__ __launch_bounds__(256) void k_ln(float* __restrict__ y,
                                            const unsigned short* __restrict__ y1,
                                            const unsigned short* __restrict__ y2,
                                            const unsigned short* __restrict__ y3,
                                            const float* __restrict__ gamma,
                                            const float* __restrict__ beta) {
    int tid = threadIdx.x;
    int w = tid >> 6, lane = tid & 63;
    int r = blockIdx.x * 4 + w;
    int b = r >> 12;
    int pos = r & 4095;
    int q = ((pos & 63) << 6) | (pos >> 6);   // y1/y3 are stored in wh-scan order
    float4 vy = *(const float4*)(y + (size_t)r * DI + lane * 4);
    ushort4v v2 = *(const ushort4v*)(y2 + (size_t)r * DI + lane * 4);
    ushort4v v1 = *(const ushort4v*)(y1 + ((size_t)b * LL + q) * DI + lane * 4);
    ushort4v v3 = *(const ushort4v*)(y3 + ((size_t)b * LL + q) * DI + lane * 4);
    float v0 = vy.x + bf2f(v2.x) + bf2f(v1.x) + bf2f(v3.x);
    float vv1 = vy.y + bf2f(v2.y) + bf2f(v1.y) + bf2f(v3.y);
    float vv2 = vy.z + bf2f(v2.z) + bf2f(v1.z) + bf2f(v3.z);
    float vv3 = vy.w + bf2f(v2.w) + bf2f(v1.w) + bf2f(v3.w);
    float a = (v0 + vv1) + (vv2 + vv3);
    float bsq = (v0 * v0 + vv1 * vv1) + (vv2 * vv2 + vv3 * vv3);
    #pragma unroll
    for (int off = 32; off; off >>= 1) {
        a += __shfl_xor(a, off);
        bsq += __shfl_xor(bsq, off);
    }
    float mu = a * (1.f / 256.f);
    float var = bsq * (1.f / 256.f) - mu * mu;
    float rs = rsqrtf(var + 1e-5f);
    float4 gm = *(const float4*)(gamma + lane * 4);
    float4 bt = *(const float4*)(beta + lane * 4);
    float4 o;
    o.x = (v0 - mu) * rs * gm.x + bt.x;
    o.y = (vv1 - mu) * rs * gm.y + bt.y;
    o.z = (vv2 - mu) * rs * gm.z + bt.z;
    o.w = (vv3 - mu) * rs * gm.w + bt.w;
    *(float4*)(y + (size_t)r * DI + lane * 4) = o;
}

// ---------- launch ----------
extern "C" void kernel_launch(void* const* d_in, const int* in_sizes, int n_in,
                              void* d_out, int out_size, void* d_ws, size_t ws_size,
                              hipStream_t stream) {
    const float* x    = (const float*)d_in[0];
    const float* ipw  = (const float*)d_in[1];
    const float* cw   = (const float*)d_in[2];
    const float* cb   = (const float*)d_in[3];
    const float* xpw  = (const float*)d_in[4];
    const float* dtw  = (const float*)d_in[5];
    const float* dtb  = (const float*)d_in[6];
    const float* alog = (const float*)d_in[7];
    const float* Ds   = (const float*)d_in[8];
    const float* gam  = (const float*)d_in[9];
    const float* bet  = (const float*)d_in[10];

    // ws layout (bytes):
    //   [0, 16777216)           carrH (bf16) -- aliases xls_pre (in_proj out, dead after conv)
    //   [16777216, 18874368)    carrG (fp32)
    //   [18874368, 27262976)    xcB   (bf16 B*L*DI)
    //   [27262976, 37748736)    P     (fp32 B*L*160, image order: [k*40: dts|B|C])
    //   [37748736, 46137344)    y1    (bf16 B*L*DI, dir1 in wh-scan order)
    //   [46137344, 54525952)    y2    (bf16 B*L*DI, dir2 row-major)
    //   [54525952, 62914560)    y3    (bf16 B*L*DI, dir3 wh-scan order)
    const size_t WS_NEED = 62914560;
    if (ws_size < WS_NEED) return;

    char* ws = (char*)d_ws;
    unsigned short* carrH = (unsigned short*)(ws + 0);
    float* carrG   = (float*)(ws + 16777216);
    float* xls_pre = (float*)(ws + 0);
    unsigned short* xcB = (unsigned short*)(ws + 18874368);
    float* P       = (float*)(ws + 27262976);
    unsigned short* y1 = (unsigned short*)(ws + 37748736);
    unsigned short* y2 = (unsigned short*)(ws + 46137344);
    unsigned short* y3 = (unsigned short*)(ws + 54525952);
    float* y       = (float*)d_out;

    k_inproj<<<1024,  256, 0, stream>>>(x, ipw, xls_pre);
    k_conv  <<<2048,  256, 0, stream>>>(xls_pre, cw, cb, xcB);
    k_proj  <<<512,   256, 0, stream>>>(xcB, xpw, P);
    k_scanA <<<2048,  256, 0, stream>>>(xcB, P, dtw, dtb, alog, carrG, carrH);
    k_scan2 <<<256,   256, 0, stream>>>(carrG, alog, carrH);
    k_scanC <<<2048,  128, 0, stream>>>(xcB, P, dtw, dtb, alog, Ds, carrH, y, y1, y2, y3);
    k_ln    <<<4096,  256, 0, stream>>>(y, y1, y2, y3, gam, bet);
}